// Round 4
// baseline (452.688 us; speedup 1.0000x reference)
//
#include <hip/hip_runtime.h>
#include <stdint.h>

// Link predictor: score[e] = MLP([src,dst,src*dst,|src-dst|]) over 500K edges.
// Round 4: 32 edges/block, 16KB LDS -> target 7-8 blocks/CU (vs 4 at 32KB).
// Gather is latency-bound (r3: HBM 18%, VALU 48%, occ 42%); double the resident
// waves to double outstanding gathers. Native __bf16 casts (HW RNE) trim VALU.
// d_ws: stage1 = W1 bf16 B-frag layout (65536 shorts), stage2 = W2 (8192 shorts).

typedef __bf16 bf16x8 __attribute__((ext_vector_type(8)));
typedef __bf16 bf16x4 __attribute__((ext_vector_type(4)));
typedef float  f32x4  __attribute__((ext_vector_type(4)));

// ---------------- prep: W1/W2 fp32 -> bf16 B-fragment layout ----------------
// stage1[((ntile*16+kstep)*64+lane)*8+j] = bf16(W1[k*128+n]),
//   k = kstep*32 + (lane>>4)*8 + j, n = ntile*16 + (lane&15).
__global__ void prep_kernel(const float* __restrict__ W1, const float* __restrict__ W2,
                            short* __restrict__ stage1, short* __restrict__ stage2) {
    int idx = blockIdx.x * 256 + threadIdx.x;
    if (idx < 65536) {
        int k = idx >> 7, n = idx & 127;
        float v = W1[idx];
        int ntile = n >> 4, ln = n & 15;
        int kstep = k >> 5, kr = k & 31;
        int lane = (kr >> 3) * 16 + ln;
        int j = kr & 7;
        __bf16 b = (__bf16)v;
        stage1[(((ntile * 16 + kstep) * 64 + lane) << 3) + j] = *(short*)&b;
    } else if (idx < 65536 + 8192) {
        int i2 = idx - 65536;
        int k = i2 >> 6, n = i2 & 63;
        float v = W2[i2];
        int ntile = n >> 4, ln = n & 15;
        int kstep = k >> 5, kr = k & 31;
        int lane = (kr >> 3) * 16 + ln;
        int j = kr & 7;
        __bf16 b = (__bf16)v;
        stage2[(((ntile * 4 + kstep) * 64 + lane) << 3) + j] = *(short*)&b;
    }
}

// ---------------- main ----------------
// 32 edges/block, 256 threads (4 waves), 16KB LDS.
// LDS: s-tile [32 x 128]bf16 at 0 (row stride 256B), d-tile at 8192.
//   16B chunk cc = k>>3 stored at physical chunk cc ^ (m&15) (XOR swizzle).
// After GEMM1: [0,8192) reused for h1 bf16 [32x128] (same swizzle).
// After GEMM2: [0,8704) holds h2 fp32 [32 x 68] (stride 272B).
__launch_bounds__(256, 4)
__global__ void link_kernel(const float* __restrict__ z,
                            const int*   __restrict__ ei,
                            const float* __restrict__ b1,
                            const float* __restrict__ b2,
                            const float* __restrict__ w3,
                            const float* __restrict__ b3,
                            const short* __restrict__ stage1,
                            const short* __restrict__ stage2,
                            float* __restrict__ out,
                            int E) {
    __shared__ __align__(16) char smem[16384];

    const int tid  = threadIdx.x;
    const int lane = tid & 63;
    const int wave = tid >> 6;
    const int ln15 = lane & 15;
    const int quad = lane >> 4;
    const int e0   = blockIdx.x * 32;

    // ---- Phase A: gather src/dst rows -> LDS bf16 (swizzled) ----
    // 32 rows x 32 float4-chunks = 1024 tasks / 256 threads = 4 iters.
    const int c    = tid & 31;
    const int mrow = tid >> 5;          // 0..7
    int si[4], di[4];
    #pragma unroll
    for (int i = 0; i < 4; ++i) {
        int eg = e0 + mrow + i * 8;
        int egc = eg < E ? eg : (E - 1);
        si[i] = ei[egc];
        di[i] = ei[E + egc];
    }
    const int cc   = c >> 1;
    const int half = c & 1;
    #pragma unroll
    for (int i = 0; i < 4; ++i) {
        int m = mrow + i * 8;
        f32x4 s = *(const f32x4*)(z + (size_t)si[i] * 128 + c * 4);
        f32x4 d = *(const f32x4*)(z + (size_t)di[i] * 128 + c * 4);
        int addr = m * 256 + ((cc ^ (m & 15)) << 4) + half * 8;
        bf16x4 ps, pd;
        #pragma unroll
        for (int j = 0; j < 4; ++j) { ps[j] = (__bf16)s[j]; pd[j] = (__bf16)d[j]; }
        *(bf16x4*)(smem + addr)        = ps;
        *(bf16x4*)(smem + 8192 + addr) = pd;
    }
    __syncthreads();

    // ---- GEMM1: A[32x512] @ W1[512x128], it/df A-frags derived in regs ----
    f32x4 acc[2][2];
    #pragma unroll
    for (int mt = 0; mt < 2; ++mt)
        #pragma unroll
        for (int nt = 0; nt < 2; ++nt)
            acc[mt][nt] = (f32x4){0.f, 0.f, 0.f, 0.f};

    #pragma unroll
    for (int ks4 = 0; ks4 < 4; ++ks4) {
        bf16x8 B[2][4];
        #pragma unroll
        for (int nt = 0; nt < 2; ++nt) {
            int ntile = wave * 2 + nt;
            #pragma unroll
            for (int f = 0; f < 4; ++f)
                B[nt][f] = *(const bf16x8*)(stage1 + (((ntile * 16 + f * 4 + ks4) * 64 + lane) << 3));
        }
        #pragma unroll
        for (int mt = 0; mt < 2; ++mt) {
            int m = mt * 16 + ln15;
            int off = m * 256 + (((ks4 * 4 + quad) ^ (m & 15)) << 4);
            bf16x8 sf = *(const bf16x8*)(smem + off);
            bf16x8 df = *(const bf16x8*)(smem + 8192 + off);
            bf16x8 itf, ddf;
            #pragma unroll
            for (int j = 0; j < 8; ++j) {
                float fs = (float)sf[j], fd = (float)df[j];
                itf[j] = (__bf16)(fs * fd);
                ddf[j] = (__bf16)__builtin_fabsf(fs - fd);
            }
            #pragma unroll
            for (int nt = 0; nt < 2; ++nt) {
                acc[mt][nt] = __builtin_amdgcn_mfma_f32_16x16x32_bf16(sf,  B[nt][0], acc[mt][nt], 0, 0, 0);
                acc[mt][nt] = __builtin_amdgcn_mfma_f32_16x16x32_bf16(df,  B[nt][1], acc[mt][nt], 0, 0, 0);
                acc[mt][nt] = __builtin_amdgcn_mfma_f32_16x16x32_bf16(itf, B[nt][2], acc[mt][nt], 0, 0, 0);
                acc[mt][nt] = __builtin_amdgcn_mfma_f32_16x16x32_bf16(ddf, B[nt][3], acc[mt][nt], 0, 0, 0);
            }
        }
    }
    __syncthreads();   // all waves done reading s/d tiles

    // ---- epilogue 1: h1 = relu(acc + b1) -> LDS bf16 [32 x 128] at 0, swizzled ----
    #pragma unroll
    for (int nt = 0; nt < 2; ++nt) {
        int n = (wave * 2 + nt) * 16 + ln15;      // = k2 for GEMM2
        float bias = b1[n];
        #pragma unroll
        for (int mt = 0; mt < 2; ++mt) {
            #pragma unroll
            for (int r = 0; r < 4; ++r) {
                int row = mt * 16 + quad * 4 + r;  // C/D: row = quad*4 + reg
                float h = acc[mt][nt][r] + bias;
                h = h > 0.f ? h : 0.f;
                int addr = row * 256 + (((n >> 3) ^ (row & 15)) << 4) + (n & 7) * 2;
                *(__bf16*)(smem + addr) = (__bf16)h;
            }
        }
    }
    __syncthreads();

    // ---- GEMM2: h1[32x128] @ W2[128x64]; wave w owns n-tile w (16 cols) ----
    f32x4 acc2[2];
    #pragma unroll
    for (int mt = 0; mt < 2; ++mt) acc2[mt] = (f32x4){0.f, 0.f, 0.f, 0.f};

    #pragma unroll
    for (int ks = 0; ks < 4; ++ks) {
        bf16x8 b = *(const bf16x8*)(stage2 + (((wave * 4 + ks) * 64 + lane) << 3));
        #pragma unroll
        for (int mt = 0; mt < 2; ++mt) {
            int m = mt * 16 + ln15;
            int ccr = ks * 4 + quad;
            bf16x8 a = *(const bf16x8*)(smem + m * 256 + ((ccr ^ (m & 15)) << 4));
            acc2[mt] = __builtin_amdgcn_mfma_f32_16x16x32_bf16(a, b, acc2[mt], 0, 0, 0);
        }
    }
    __syncthreads();   // all waves done reading h1

    // ---- epilogue 2: h2 = relu(acc2 + b2) -> LDS fp32 [32 x 68] at 0 ----
    {
        int n2 = wave * 16 + ln15;
        float bias = b2[n2];
        #pragma unroll
        for (int mt = 0; mt < 2; ++mt) {
            #pragma unroll
            for (int r = 0; r < 4; ++r) {
                int row = mt * 16 + quad * 4 + r;
                float h = acc2[mt][r] + bias;
                h = h > 0.f ? h : 0.f;
                *(float*)(smem + row * 272 + n2 * 4) = h;
            }
        }
    }
    __syncthreads();

    // ---- final: score = h2 . W3 + b3 (fp32), wave 0 lanes 0..31, one lane/edge ----
    if (wave == 0 && lane < 32) {
        int e = lane;
        float accf = b3[0];
        const float* h2p = (const float*)(smem + e * 272);
        #pragma unroll
        for (int kk = 0; kk < 16; ++kk) {
            f32x4 h = *(const f32x4*)(h2p + kk * 4);
            f32x4 w = *(const f32x4*)(w3 + kk * 4);
            accf += h[0] * w[0] + h[1] * w[1] + h[2] * w[2] + h[3] * w[3];
        }
        if (e0 + e < E) out[e0 + e] = accf;
    }
}

extern "C" void kernel_launch(void* const* d_in, const int* in_sizes, int n_in,
                              void* d_out, int out_size, void* d_ws, size_t ws_size,
                              hipStream_t stream) {
    const float* z  = (const float*)d_in[0];
    const int*   ei = (const int*)  d_in[1];
    const float* W1 = (const float*)d_in[2];
    const float* b1 = (const float*)d_in[3];
    const float* W2 = (const float*)d_in[4];
    const float* b2 = (const float*)d_in[5];
    const float* W3 = (const float*)d_in[6];
    const float* b3 = (const float*)d_in[7];
    float* out = (float*)d_out;

    int E = in_sizes[1] / 2;

    short* stage1 = (short*)d_ws;          // 65536 shorts = 128 KB
    short* stage2 = stage1 + 65536;        // 8192 shorts  = 16 KB

    prep_kernel<<<288, 256, 0, stream>>>(W1, W2, stage1, stage2);

    int nblk = (E + 31) / 32;
    link_kernel<<<nblk, 256, 0, stream>>>(z, ei, b1, b2, W3, b3, stage1, stage2, out, E);
}